// Round 9
// baseline (16474.890 us; speedup 1.0000x reference)
//
#include <hip/hip_runtime.h>
#include <math.h>

#define SS   2048
#define HH   1024
#define HHF  512
#define NWG  192
#define REC_WGS 128
#define NTH  256

__device__ __forceinline__ float dot4f(float4 a, float4 b){
  return a.x*b.x + a.y*b.y + a.z*b.z + a.w*b.w;
}

// relaxed agent-scope atomics -> sc1 (L2-bypass, coherent at L3)
__device__ __forceinline__ float2 aload2(const float* p){
  unsigned long long v = __hip_atomic_load((const unsigned long long*)p,
                                           __ATOMIC_RELAXED, __HIP_MEMORY_SCOPE_AGENT);
  union { unsigned long long u; float2 f; } c; c.u = v; return c.f;
}
__device__ __forceinline__ void astore1(float* p, float v){
  __hip_atomic_store(p, v, __ATOMIC_RELAXED, __HIP_MEMORY_SCOPE_AGENT);
}
__device__ __forceinline__ float aload1(const float* p){
  return __hip_atomic_load(p, __ATOMIC_RELAXED, __HIP_MEMORY_SCOPE_AGENT);
}
__device__ __forceinline__ unsigned uload(const unsigned* p){
  return __hip_atomic_load(p, __ATOMIC_RELAXED, __HIP_MEMORY_SCOPE_AGENT);
}

// ---------- transpose h-part of tau_w1: w1hT[m][i] = tau_w1[1024+i][m] ----------
__global__ __launch_bounds__(256) void transpose_w1h(const float* __restrict__ tw1,
                                                     float* __restrict__ w1hT){
  __shared__ float ts[32][33];
  int c  = threadIdx.x & 31;
  int r4 = (threadIdx.x >> 5) * 4;
  int bi = blockIdx.x * 32;
  int bm = blockIdx.y * 32;
  #pragma unroll
  for (int rr = 0; rr < 4; ++rr)
    ts[r4+rr][c] = tw1[(size_t)(1024 + bi + r4 + rr) * 512 + bm + c];
  __syncthreads();
  #pragma unroll
  for (int rr = 0; rr < 4; ++rr)
    w1hT[(size_t)(bm + r4 + rr) * 1024 + bi + c] = ts[c][r4+rr];
}

// ---------- xtau[r][m] = X[r][:] @ tau_w1[:1024][m] + b1[m] ----------
__global__ __launch_bounds__(256) void gemm_xtau(const float* __restrict__ X,
                                                 const float* __restrict__ tw1,
                                                 const float* __restrict__ b1,
                                                 float* __restrict__ xtau){
  __shared__ float Xs[16][68];
  __shared__ float Ws[16][68];
  const int tid = threadIdx.x;
  const int tx = tid & 15, ty = tid >> 4;
  const int rowbase = blockIdx.y * 64;
  const int colbase = blockIdx.x * 64;
  const int xr  = tid >> 2,  xk4 = (tid & 3) * 4;
  const int wr  = tid >> 4,  wc4 = (tid & 15) * 4;
  float acc[4][4];
  #pragma unroll
  for (int i=0;i<4;++i){
    #pragma unroll
    for (int j=0;j<4;++j) acc[i][j]=0.f;
  }
  for (int k0 = 0; k0 < 1024; k0 += 16){
    float4 xv = *(const float4*)&X  [(size_t)(rowbase + xr)*1024 + k0 + xk4];
    float4 wv = *(const float4*)&tw1[(size_t)(k0 + wr)*512 + colbase + wc4];
    __syncthreads();
    Xs[xk4+0][xr]=xv.x; Xs[xk4+1][xr]=xv.y; Xs[xk4+2][xr]=xv.z; Xs[xk4+3][xr]=xv.w;
    *(float4*)&Ws[wr][wc4] = wv;
    __syncthreads();
    #pragma unroll
    for (int kk=0;kk<16;++kk){
      float4 av = *(const float4*)&Xs[kk][ty*4];
      float4 bv = *(const float4*)&Ws[kk][tx*4];
      acc[0][0]+=av.x*bv.x; acc[0][1]+=av.x*bv.y; acc[0][2]+=av.x*bv.z; acc[0][3]+=av.x*bv.w;
      acc[1][0]+=av.y*bv.x; acc[1][1]+=av.y*bv.y; acc[1][2]+=av.y*bv.z; acc[1][3]+=av.y*bv.w;
      acc[2][0]+=av.z*bv.x; acc[2][1]+=av.z*bv.y; acc[2][2]+=av.z*bv.z; acc[2][3]+=av.z*bv.w;
      acc[3][0]+=av.w*bv.x; acc[3][1]+=av.w*bv.y; acc[3][2]+=av.w*bv.z; acc[3][3]+=av.w*bv.w;
    }
  }
  float4 bias = *(const float4*)&b1[colbase + tx*4];
  #pragma unroll
  for (int i=0;i<4;++i){
    float4 o;
    o.x=acc[i][0]+bias.x; o.y=acc[i][1]+bias.y; o.z=acc[i][2]+bias.z; o.w=acc[i][3]+bias.w;
    *(float4*)&xtau[(size_t)(rowbase + ty*4 + i)*512 + colbase + tx*4] = o;
  }
}

// ---------- persistent liquid recurrence ----------
// R2 control structure (publish once / barrier / load once) with the
// serialization chains removed:
//  - tau partials: distinct slots, consumer-side reduce (no 64-deep RMW)
//  - arrive: 16 striped counters (12-deep chains, not 48)
//  - no store-ack drain before arrive; data validity carried by mod-4 tags,
//    revalidated once post-release (bounded by store flight time)
//  - speculative f/tau loads in flight during the poll
__global__ __launch_bounds__(256, 1) void liquid_kernel(
    const float* __restrict__ X, const float* __restrict__ Wrec,
    const float* __restrict__ w1hT, const float* __restrict__ tw2,
    const float* __restrict__ tb2, const float* __restrict__ lng,
    const float* __restrict__ lnb, const float* __restrict__ xtau,
    unsigned* __restrict__ cnt, float* __restrict__ fbuf,
    float* __restrict__ taup, float* __restrict__ out)
{
  __shared__ float hs[2][4][1024];

  const int tid  = threadIdx.x;
  const int wv   = tid >> 6;      // wave == batch
  const int lane = tid & 63;
  const int wg   = blockIdx.x;

  for (int p = tid; p < 8192; p += NTH) (&hs[0][0][0])[p] = 0.f;

  // 8 virtual rows per WG (2 per wave) resident in VGPRs
  float4 wreg[2][4];
  #pragma unroll
  for (int rr = 0; rr < 2; ++rr){
    int vrow = wg*8 + wv*2 + rr;
    const float* wrow = (vrow < 1024) ? (Wrec + (size_t)vrow*1024)
                                      : (w1hT + (size_t)(vrow - 1024)*1024);
    #pragma unroll
    for (int k = 0; k < 4; ++k)
      wreg[rr][k] = *(const float4*)&wrow[4*lane + 256*k];
  }
  float4 g4[4], be4[4];
  #pragma unroll
  for (int k = 0; k < 4; ++k){
    g4[k]  = *(const float4*)&lng[4*lane + 256*k];
    be4[k] = *(const float4*)&lnb[4*lane + 256*k];
  }
  const float b2 = tb2[0];
  float w2r0 = 0.f, w2r1 = 0.f;
  if (wg >= REC_WGS){
    w2r0 = tw2[(wg - REC_WGS)*8 + wv*2 + 0];
    w2r1 = tw2[(wg - REC_WGS)*8 + wv*2 + 1];
  }
  __syncthreads();

  for (int t = 0; t < SS; ++t){
    const int cur = t & 1, nxt = cur ^ 1;
    // mod-4 tags: slot holds step t or t-2 only (barrier-bounded), diff 4 (f)
    // / 16 (tau) is outside the windows; zero-init invalid.
    const float fbase = 2.f*(float)((t & 3) + 1);   // 2,4,6,8  window +-1.05
    const float tbase = 8.f*(float)((t & 3) + 1);   // 8,16,24,32 window +-2.0

    // ---- x / xtau preload (lanes 0..7 per wave)
    float xpre = 0.f;
    if (lane < 8){
      const int rr = lane >> 2, b = lane & 3;
      if (wg < REC_WGS)
        xpre = X[((size_t)b*SS + t)*HH + wg*8 + wv*2 + rr];
      else
        xpre = xtau[((size_t)b*SS + t)*HHF + (wg - REC_WGS)*8 + wv*2 + rr];
    }

    // ---- matvec: 2 rows x 4 batches per wave, weights in regs, h from LDS
    float acc[8];
    #pragma unroll
    for (int a=0;a<8;++a) acc[a]=0.f;
    #pragma unroll
    for (int k=0;k<4;++k){
      const int off = 4*lane + 256*k;
      float4 h0 = *(const float4*)&hs[cur][0][off];
      float4 h1 = *(const float4*)&hs[cur][1][off];
      float4 h2 = *(const float4*)&hs[cur][2][off];
      float4 h3 = *(const float4*)&hs[cur][3][off];
      #pragma unroll
      for (int rr=0;rr<2;++rr){
        acc[rr*4+0] += dot4f(wreg[rr][k], h0);
        acc[rr*4+1] += dot4f(wreg[rr][k], h1);
        acc[rr*4+2] += dot4f(wreg[rr][k], h2);
        acc[rr*4+3] += dot4f(wreg[rr][k], h3);
      }
    }
    #pragma unroll
    for (int a=0;a<8;++a){
      float v = acc[a];
      #pragma unroll
      for (int o=32;o>0;o>>=1) v += __shfl_xor(v, o, 64);
      acc[a]=v;
    }
    float sel = acc[0];
    sel = (lane==1)?acc[1]:sel; sel = (lane==2)?acc[2]:sel;
    sel = (lane==3)?acc[3]:sel; sel = (lane==4)?acc[4]:sel;
    sel = (lane==5)?acc[5]:sel; sel = (lane==6)?acc[6]:sel;
    sel = (lane==7)?acc[7]:sel;
    float fval = tanhf(xpre + sel);

    // ---- tagged publish (plain sc1 stores to distinct slots; zero RMW)
    if (wg < REC_WGS){
      if (lane < 8)
        astore1(&fbuf[cur*4096 + (lane&3)*1024 + wg*8 + wv*2 + (lane>>2)],
                fbase + fval);
    } else {
      float w2s = (lane & 4) ? w2r1 : w2r0;
      float contrib = fval * w2s;
      contrib += __shfl_xor(contrib, 4, 64);   // sum this wave's 2 rows
      if (lane < 4)
        astore1(&taup[cur*1024 + lane*256 + (wg - REC_WGS)*4 + wv],
                tbase + contrib);
    }

    // ---- all 4 waves have ISSUED their publishes (no completion drain)
    __builtin_amdgcn_sched_barrier(0);
    __builtin_amdgcn_s_barrier();

    // ---- arrive: 16 striped counters, 12-deep chains (relaxed, no-return)
    if (tid == 0)
      __hip_atomic_fetch_add(&cnt[(wg & 15)*16], 1u,
                             __ATOMIC_RELAXED, __HIP_MEMORY_SCOPE_AGENT);

    // ---- speculative consumer loads: in flight during the poll
    const float* fb = fbuf + cur*4096 + wv*1024;
    float2 pr[8]; float tv[4];
    #pragma unroll
    for (int q=0;q<8;++q)
      pr[q] = aload2(&fb[(q>>1)*256 + 4*lane + (q&1)*2]);
    #pragma unroll
    for (int j=0;j<4;++j)
      tv[j] = aload1(&taup[cur*1024 + wv*256 + lane + 64*j]);

    // ---- poll: wave 0 only; all lanes load cnt[lane&15], butterfly over 16
    if (wv == 0){
      const unsigned tgt = (unsigned)NWG * (unsigned)(t + 1);
      int guard = 0;
      while (true){
        unsigned s = uload(&cnt[(lane & 15)*16]);
        #pragma unroll
        for (int o=8;o>0;o>>=1) s += (unsigned)__shfl_xor((int)s, o, 64);
        if (s >= tgt) break;
        if (++guard > 4000000) break;
      }
    }
    asm volatile("" ::: "memory");
    __builtin_amdgcn_s_barrier();   // release all waves
    asm volatile("" ::: "memory");

    // ---- revalidate tags; reload until valid (bounded by store flight)
    int guard = 0;
    while (true){
      bool all = true;
      #pragma unroll
      for (int q=0;q<8;++q){
        bool ok = (fabsf(pr[q].x - fbase) < 1.05f) && (fabsf(pr[q].y - fbase) < 1.05f);
        if (!ok){ all = false; pr[q] = aload2(&fb[(q>>1)*256 + 4*lane + (q&1)*2]); }
      }
      #pragma unroll
      for (int j=0;j<4;++j){
        if (!(fabsf(tv[j] - tbase) < 2.0f)){
          all = false; tv[j] = aload1(&taup[cur*1024 + wv*256 + lane + 64*j]);
        }
      }
      if (all) break;
      if (++guard > 100000) break;
    }

    // ---- tau (intra-wave reduce of 256 partials: 4 per lane)
    float tpart = (tv[0]-tbase)+(tv[1]-tbase)+(tv[2]-tbase)+(tv[3]-tbase);
    #pragma unroll
    for (int o=32;o>0;o>>=1) tpart += __shfl_xor(tpart, o, 64);
    float pre = tpart + b2;
    float sig = 1.f / (1.f + expf(-pre));
    float al  = 0.1f / (1.f + 4.f*sig);

    // ---- h' + LN (fully intra-wave, batch = wv)
    float s1 = 0.f, s2 = 0.f;
    float4 hp4[4];
    #pragma unroll
    for (int k=0;k<4;++k){
      const int off = 4*lane + 256*k;
      float4 h4 = *(const float4*)&hs[cur][wv][off];
      float4 hp;
      hp.x = h4.x + al*((pr[2*k  ].x - fbase) - h4.x);
      hp.y = h4.y + al*((pr[2*k  ].y - fbase) - h4.y);
      hp.z = h4.z + al*((pr[2*k+1].x - fbase) - h4.z);
      hp.w = h4.w + al*((pr[2*k+1].y - fbase) - h4.w);
      hp4[k] = hp;
      s1 += hp.x + hp.y + hp.z + hp.w;
      s2 += hp.x*hp.x + hp.y*hp.y + hp.z*hp.z + hp.w*hp.w;
    }
    #pragma unroll
    for (int o=32;o>0;o>>=1){
      s1 += __shfl_xor(s1, o, 64);
      s2 += __shfl_xor(s2, o, 64);
    }
    float mu   = s1 * (1.f/1024.f);
    float var  = s2 * (1.f/1024.f) - mu*mu;
    float rstd = rsqrtf(var + 1e-5f);
    #pragma unroll
    for (int k=0;k<4;++k){
      const int off = 4*lane + 256*k;
      float4 hp = hp4[k];
      float4 o4;
      o4.x = (hp.x - mu)*rstd*g4[k].x + be4[k].x;
      o4.y = (hp.y - mu)*rstd*g4[k].y + be4[k].y;
      o4.z = (hp.z - mu)*rstd*g4[k].z + be4[k].z;
      o4.w = (hp.w - mu)*rstd*g4[k].w + be4[k].w;
      *(float4*)&hs[nxt][wv][off] = o4;
      if (wg < 16 && (wg >> 2) == k && (lane >> 4) == (wg & 3))
        *(float4*)&out[((size_t)wv*SS + t)*HH + off] = o4;
    }

    // ---- end-of-step: wait only LDS writes (global stores keep flying)
    asm volatile("s_waitcnt lgkmcnt(0)" ::: "memory");
    __builtin_amdgcn_sched_barrier(0);
    __builtin_amdgcn_s_barrier();
  }
}

// ---------- out = sc + 0.01*(liq - sc), in place over liq ----------
__global__ __launch_bounds__(256) void finalize_kernel(const float* __restrict__ X,
                                                       const float* __restrict__ cw,
                                                       float* __restrict__ out){
  size_t gid = (size_t)blockIdx.x * 256 + threadIdx.x;
  size_t gi  = gid * 4;
  int b   = (int)(gi >> 21);
  int rem = (int)(gi & 2097151);
  int t   = rem >> 10;
  int i   = rem & 1023;
  float4 l4 = *(const float4*)&out[gi];
  const float* xb = X + ((size_t)b*SS)*HH + i;
  float4 z4 = make_float4(0.f,0.f,0.f,0.f);
  float4 xk0 = (t >= 3) ? *(const float4*)&xb[(size_t)(t-3)*HH] : z4;
  float4 xk1 = (t >= 2) ? *(const float4*)&xb[(size_t)(t-2)*HH] : z4;
  float4 xk2 = (t >= 1) ? *(const float4*)&xb[(size_t)(t-1)*HH] : z4;
  float4 xk3 =            *(const float4*)&xb[(size_t)t*HH];
  float4 cw0 = *(const float4*)&cw[(i+0)*4];
  float4 cw1 = *(const float4*)&cw[(i+1)*4];
  float4 cw2 = *(const float4*)&cw[(i+2)*4];
  float4 cw3 = *(const float4*)&cw[(i+3)*4];
  float4 sc;
  sc.x = cw0.x*xk0.x + cw0.y*xk1.x + cw0.z*xk2.x + cw0.w*xk3.x;
  sc.y = cw1.x*xk0.y + cw1.y*xk1.y + cw1.z*xk2.y + cw1.w*xk3.y;
  sc.z = cw2.x*xk0.z + cw2.y*xk1.z + cw2.z*xk2.z + cw2.w*xk3.z;
  sc.w = cw3.x*xk0.w + cw3.y*xk1.w + cw3.z*xk2.w + cw3.w*xk3.w;
  float4 o;
  o.x = sc.x + 0.01f*(l4.x - sc.x);
  o.y = sc.y + 0.01f*(l4.y - sc.y);
  o.z = sc.z + 0.01f*(l4.z - sc.z);
  o.w = sc.w + 0.01f*(l4.w - sc.w);
  *(float4*)&out[gi] = o;
}

extern "C" void kernel_launch(void* const* d_in, const int* in_sizes, int n_in,
                              void* d_out, int out_size, void* d_ws, size_t ws_size,
                              hipStream_t stream) {
  const float* X     = (const float*)d_in[0];
  const float* convw = (const float*)d_in[1];
  const float* Wrec  = (const float*)d_in[2];
  const float* tw1   = (const float*)d_in[3];
  const float* tb1   = (const float*)d_in[4];
  const float* tw2   = (const float*)d_in[5];
  const float* tb2   = (const float*)d_in[6];
  const float* lng   = (const float*)d_in[7];
  const float* lnb   = (const float*)d_in[8];
  float* out = (float*)d_out;
  float* wsf = (float*)d_ws;

  unsigned* cnt = (unsigned*)d_ws;      // 16 counters @ 64B spacing = 256 dwords
  float* fbuf = wsf + 256;              // 2 x 4 x 1024 tagged f
  float* taup = wsf + 8448;             // 2 x 4 x 256 tagged tau partials
  float* w1hT = wsf + 10496;            // 512 x 1024
  float* xtau = w1hT + 512*1024;        // 8192 x 512

  hipMemsetAsync(d_ws, 0, 41984, stream);  // counters + all tags invalid
  transpose_w1h<<<dim3(32,16), dim3(256), 0, stream>>>(tw1, w1hT);
  gemm_xtau   <<<dim3(8,128),  dim3(256), 0, stream>>>(X, tw1, tb1, xtau);
  liquid_kernel<<<dim3(NWG),   dim3(NTH), 0, stream>>>(X, Wrec, w1hT, tw2, tb2,
                                                       lng, lnb, xtau, cnt, fbuf,
                                                       taup, out);
  finalize_kernel<<<dim3(8192), dim3(256), 0, stream>>>(X, convw, out);
}

// Round 11
// 10136.994 us; speedup vs baseline: 1.6252x; 1.6252x over previous
//
#include <hip/hip_runtime.h>
#include <math.h>

#define SS   2048
#define HH   1024
#define HHF  512
#define NWG  192
#define REC_WGS 128
#define NTH  256
#define NCNT 16

__device__ __forceinline__ float dot4f(float4 a, float4 b){
  return a.x*b.x + a.y*b.y + a.z*b.z + a.w*b.w;
}

// relaxed agent-scope atomics -> sc1 (L2-bypass, coherent at L3)
__device__ __forceinline__ float2 aload2(const float* p){
  unsigned long long v = __hip_atomic_load((const unsigned long long*)p,
                                           __ATOMIC_RELAXED, __HIP_MEMORY_SCOPE_AGENT);
  union { unsigned long long u; float2 f; } c; c.u = v; return c.f;
}
__device__ __forceinline__ void astore1(float* p, float v){
  __hip_atomic_store(p, v, __ATOMIC_RELAXED, __HIP_MEMORY_SCOPE_AGENT);
}
__device__ __forceinline__ float aload1(const float* p){
  return __hip_atomic_load(p, __ATOMIC_RELAXED, __HIP_MEMORY_SCOPE_AGENT);
}
__device__ __forceinline__ unsigned uload(const unsigned* p){
  return __hip_atomic_load(p, __ATOMIC_RELAXED, __HIP_MEMORY_SCOPE_AGENT);
}

// ---------- transpose h-part of tau_w1: w1hT[m][i] = tau_w1[1024+i][m] ----------
__global__ __launch_bounds__(256) void transpose_w1h(const float* __restrict__ tw1,
                                                     float* __restrict__ w1hT){
  __shared__ float ts[32][33];
  int c  = threadIdx.x & 31;
  int r4 = (threadIdx.x >> 5) * 4;
  int bi = blockIdx.x * 32;
  int bm = blockIdx.y * 32;
  #pragma unroll
  for (int rr = 0; rr < 4; ++rr)
    ts[r4+rr][c] = tw1[(size_t)(1024 + bi + r4 + rr) * 512 + bm + c];
  __syncthreads();
  #pragma unroll
  for (int rr = 0; rr < 4; ++rr)
    w1hT[(size_t)(bm + r4 + rr) * 1024 + bi + c] = ts[c][r4+rr];
}

// ---------- xtau[r][m] = X[r][:] @ tau_w1[:1024][m] + b1[m] ----------
__global__ __launch_bounds__(256) void gemm_xtau(const float* __restrict__ X,
                                                 const float* __restrict__ tw1,
                                                 const float* __restrict__ b1,
                                                 float* __restrict__ xtau){
  __shared__ float Xs[16][68];
  __shared__ float Ws[16][68];
  const int tid = threadIdx.x;
  const int tx = tid & 15, ty = tid >> 4;
  const int rowbase = blockIdx.y * 64;
  const int colbase = blockIdx.x * 64;
  const int xr  = tid >> 2,  xk4 = (tid & 3) * 4;
  const int wr  = tid >> 4,  wc4 = (tid & 15) * 4;
  float acc[4][4];
  #pragma unroll
  for (int i=0;i<4;++i){
    #pragma unroll
    for (int j=0;j<4;++j) acc[i][j]=0.f;
  }
  for (int k0 = 0; k0 < 1024; k0 += 16){
    float4 xv = *(const float4*)&X  [(size_t)(rowbase + xr)*1024 + k0 + xk4];
    float4 wv = *(const float4*)&tw1[(size_t)(k0 + wr)*512 + colbase + wc4];
    __syncthreads();
    Xs[xk4+0][xr]=xv.x; Xs[xk4+1][xr]=xv.y; Xs[xk4+2][xr]=xv.z; Xs[xk4+3][xr]=xv.w;
    *(float4*)&Ws[wr][wc4] = wv;
    __syncthreads();
    #pragma unroll
    for (int kk=0;kk<16;++kk){
      float4 av = *(const float4*)&Xs[kk][ty*4];
      float4 bv = *(const float4*)&Ws[kk][tx*4];
      acc[0][0]+=av.x*bv.x; acc[0][1]+=av.x*bv.y; acc[0][2]+=av.x*bv.z; acc[0][3]+=av.x*bv.w;
      acc[1][0]+=av.y*bv.x; acc[1][1]+=av.y*bv.y; acc[1][2]+=av.y*bv.z; acc[1][3]+=av.y*bv.w;
      acc[2][0]+=av.z*bv.x; acc[2][1]+=av.z*bv.y; acc[2][2]+=av.z*bv.z; acc[2][3]+=av.z*bv.w;
      acc[3][0]+=av.w*bv.x; acc[3][1]+=av.w*bv.y; acc[3][2]+=av.w*bv.z; acc[3][3]+=av.w*bv.w;
    }
  }
  float4 bias = *(const float4*)&b1[colbase + tx*4];
  #pragma unroll
  for (int i=0;i<4;++i){
    float4 o;
    o.x=acc[i][0]+bias.x; o.y=acc[i][1]+bias.y; o.z=acc[i][2]+bias.z; o.w=acc[i][3]+bias.w;
    *(float4*)&xtau[(size_t)(rowbase + ty*4 + i)*512 + colbase + tx*4] = o;
  }
}

// ---------- persistent liquid recurrence ----------
// R2's proven skeleton: publish -> DRAIN(vmcnt0) -> arrive -> paced poll ->
// release -> load ONCE. Changes vs R2 (both individually proven in R6-R9):
//  - tau partials to distinct slots + consumer-side wave reduce (no 64-deep
//    same-address RMW chain)
//  - arrive on 16 striped counters (12-deep chains, not 48)
//  - poll: wave0 lanes 0..15 only (uniform exit mask!), butterfly over 16,
//    s_sleep backoff, small guard (fail-visible, never watchdog)
__global__ __launch_bounds__(256, 1) void liquid_kernel(
    const float* __restrict__ X, const float* __restrict__ Wrec,
    const float* __restrict__ w1hT, const float* __restrict__ tw2,
    const float* __restrict__ tb2, const float* __restrict__ lng,
    const float* __restrict__ lnb, const float* __restrict__ xtau,
    unsigned* __restrict__ cnt, float* __restrict__ fbuf,
    float* __restrict__ taup, float* __restrict__ out)
{
  __shared__ float hs[2][4][1024];

  const int tid  = threadIdx.x;
  const int wv   = tid >> 6;      // wave == batch
  const int lane = tid & 63;
  const int wg   = blockIdx.x;

  for (int p = tid; p < 8192; p += NTH) (&hs[0][0][0])[p] = 0.f;

  // 8 virtual rows per WG (2 per wave) resident in VGPRs
  float4 wreg[2][4];
  #pragma unroll
  for (int rr = 0; rr < 2; ++rr){
    const float* wrow = (wg < REC_WGS)
        ? (Wrec + (size_t)(wg*8 + wv*2 + rr)*1024)
        : (w1hT + (size_t)((wg - REC_WGS)*8 + wv*2 + rr)*1024);
    #pragma unroll
    for (int k = 0; k < 4; ++k)
      wreg[rr][k] = *(const float4*)&wrow[4*lane + 256*k];
  }
  float4 g4[4], be4[4];
  #pragma unroll
  for (int k = 0; k < 4; ++k){
    g4[k]  = *(const float4*)&lng[4*lane + 256*k];
    be4[k] = *(const float4*)&lnb[4*lane + 256*k];
  }
  const float b2 = tb2[0];
  float w2r0 = 0.f, w2r1 = 0.f;
  if (wg >= REC_WGS){
    w2r0 = tw2[(wg - REC_WGS)*8 + wv*2 + 0];
    w2r1 = tw2[(wg - REC_WGS)*8 + wv*2 + 1];
  }
  __syncthreads();

  for (int t = 0; t < SS; ++t){
    const int cur = t & 1, nxt = cur ^ 1;

    // ---- x / xtau preload (lanes 0..7 per wave; 2 rows x 4 batches)
    float xpre = 0.f;
    if (lane < 8){
      const int rr = lane >> 2, b = lane & 3;
      if (wg < REC_WGS)
        xpre = X[((size_t)b*SS + t)*HH + wg*8 + wv*2 + rr];
      else
        xpre = xtau[((size_t)b*SS + t)*HHF + (wg - REC_WGS)*8 + wv*2 + rr];
    }

    // ---- matvec: 2 rows x 4 batches per wave, weights in regs, h from LDS
    float acc[8];
    #pragma unroll
    for (int a=0;a<8;++a) acc[a]=0.f;
    #pragma unroll
    for (int k=0;k<4;++k){
      const int off = 4*lane + 256*k;
      float4 h0 = *(const float4*)&hs[cur][0][off];
      float4 h1 = *(const float4*)&hs[cur][1][off];
      float4 h2 = *(const float4*)&hs[cur][2][off];
      float4 h3 = *(const float4*)&hs[cur][3][off];
      #pragma unroll
      for (int rr=0;rr<2;++rr){
        acc[rr*4+0] += dot4f(wreg[rr][k], h0);
        acc[rr*4+1] += dot4f(wreg[rr][k], h1);
        acc[rr*4+2] += dot4f(wreg[rr][k], h2);
        acc[rr*4+3] += dot4f(wreg[rr][k], h3);
      }
    }
    #pragma unroll
    for (int a=0;a<8;++a){
      float v = acc[a];
      #pragma unroll
      for (int o=32;o>0;o>>=1) v += __shfl_xor(v, o, 64);
      acc[a]=v;
    }
    float sel = acc[0];
    sel = (lane==1)?acc[1]:sel; sel = (lane==2)?acc[2]:sel;
    sel = (lane==3)?acc[3]:sel; sel = (lane==4)?acc[4]:sel;
    sel = (lane==5)?acc[5]:sel; sel = (lane==6)?acc[6]:sel;
    sel = (lane==7)?acc[7]:sel;
    float fval = tanhf(xpre + sel);

    // ---- publish (plain sc1 stores to distinct slots; zero RMW on data)
    if (wg < REC_WGS){
      if (lane < 8)
        astore1(&fbuf[cur*4096 + (lane&3)*1024 + wg*8 + wv*2 + (lane>>2)], fval);
    } else {
      float w2s = (lane & 4) ? w2r1 : w2r0;
      float contrib = fval * w2s;
      contrib += __shfl_xor(contrib, 4, 64);   // sum this wave's 2 rows
      if (lane < 4)
        astore1(&taup[cur*1024 + lane*256 + (wg - REC_WGS)*4 + wv], contrib);
    }

    // ---- DRAIN: publishes ACKed at L3 (vmcnt(0) inside __syncthreads)
    __syncthreads();
    // ---- arrive: 16 striped counters (12-deep chains)
    if (tid == 0)
      __hip_atomic_fetch_add(&cnt[(wg & (NCNT-1))*16], 1u,
                             __ATOMIC_RELAXED, __HIP_MEMORY_SCOPE_AGENT);

    // ---- poll: wave0 lanes 0..15 ONLY (uniform exit within active mask)
    if (wv == 0 && lane < NCNT){
      const unsigned tgt = (unsigned)NWG * (unsigned)(t + 1);
      int guard = 0;
      while (true){
        unsigned s = uload(&cnt[lane*16]);
        #pragma unroll
        for (int o=8;o>0;o>>=1) s += (unsigned)__shfl_xor((int)s, o, 64);
        if (s >= tgt) break;                 // same s on all 16 active lanes
        __builtin_amdgcn_s_sleep(1);
        if (++guard > 100000) break;         // fail-visible, never watchdog
      }
    }
    __syncthreads();   // release

    // ---- load ONCE (guaranteed fresh: all publishes ACKed before release)
    const float* fb = fbuf + cur*4096 + wv*1024;
    float2 pr[8]; float tv[4];
    #pragma unroll
    for (int q=0;q<8;++q)
      pr[q] = aload2(&fb[(q>>1)*256 + 4*lane + (q&1)*2]);
    #pragma unroll
    for (int j=0;j<4;++j)
      tv[j] = aload1(&taup[cur*1024 + wv*256 + lane + 64*j]);

    // ---- tau (intra-wave reduce of 256 partials: 4 per lane)
    float tpart = tv[0] + tv[1] + tv[2] + tv[3];
    #pragma unroll
    for (int o=32;o>0;o>>=1) tpart += __shfl_xor(tpart, o, 64);
    float pre = tpart + b2;
    float sig = 1.f / (1.f + expf(-pre));
    float al  = 0.1f / (1.f + 4.f*sig);

    // ---- h' + LN (fully intra-wave, batch = wv)
    float s1 = 0.f, s2 = 0.f;
    float4 hp4[4];
    #pragma unroll
    for (int k=0;k<4;++k){
      const int off = 4*lane + 256*k;
      float4 h4 = *(const float4*)&hs[cur][wv][off];
      float4 hp;
      hp.x = h4.x + al*(pr[2*k  ].x - h4.x);
      hp.y = h4.y + al*(pr[2*k  ].y - h4.y);
      hp.z = h4.z + al*(pr[2*k+1].x - h4.z);
      hp.w = h4.w + al*(pr[2*k+1].y - h4.w);
      hp4[k] = hp;
      s1 += hp.x + hp.y + hp.z + hp.w;
      s2 += hp.x*hp.x + hp.y*hp.y + hp.z*hp.z + hp.w*hp.w;
    }
    #pragma unroll
    for (int o=32;o>0;o>>=1){
      s1 += __shfl_xor(s1, o, 64);
      s2 += __shfl_xor(s2, o, 64);
    }
    float mu   = s1 * (1.f/1024.f);
    float var  = s2 * (1.f/1024.f) - mu*mu;
    float rstd = rsqrtf(var + 1e-5f);
    #pragma unroll
    for (int k=0;k<4;++k){
      const int off = 4*lane + 256*k;
      float4 hp = hp4[k];
      float4 o4;
      o4.x = (hp.x - mu)*rstd*g4[k].x + be4[k].x;
      o4.y = (hp.y - mu)*rstd*g4[k].y + be4[k].y;
      o4.z = (hp.z - mu)*rstd*g4[k].z + be4[k].z;
      o4.w = (hp.w - mu)*rstd*g4[k].w + be4[k].w;
      *(float4*)&hs[nxt][wv][off] = o4;
      if (wg < 16 && (wg >> 2) == k && (lane >> 4) == (wg & 3))
        *(float4*)&out[((size_t)wv*SS + t)*HH + off] = o4;
    }

    // ---- end-of-step: wait only LDS writes (global stores keep flying)
    asm volatile("s_waitcnt lgkmcnt(0)" ::: "memory");
    __builtin_amdgcn_sched_barrier(0);
    __builtin_amdgcn_s_barrier();
  }
}

// ---------- out = sc + 0.01*(liq - sc), in place over liq ----------
__global__ __launch_bounds__(256) void finalize_kernel(const float* __restrict__ X,
                                                       const float* __restrict__ cw,
                                                       float* __restrict__ out){
  size_t gid = (size_t)blockIdx.x * 256 + threadIdx.x;
  size_t gi  = gid * 4;
  int b   = (int)(gi >> 21);
  int rem = (int)(gi & 2097151);
  int t   = rem >> 10;
  int i   = rem & 1023;
  float4 l4 = *(const float4*)&out[gi];
  const float* xb = X + ((size_t)b*SS)*HH + i;
  float4 z4 = make_float4(0.f,0.f,0.f,0.f);
  float4 xk0 = (t >= 3) ? *(const float4*)&xb[(size_t)(t-3)*HH] : z4;
  float4 xk1 = (t >= 2) ? *(const float4*)&xb[(size_t)(t-2)*HH] : z4;
  float4 xk2 = (t >= 1) ? *(const float4*)&xb[(size_t)(t-1)*HH] : z4;
  float4 xk3 =            *(const float4*)&xb[(size_t)t*HH];
  float4 cw0 = *(const float4*)&cw[(i+0)*4];
  float4 cw1 = *(const float4*)&cw[(i+1)*4];
  float4 cw2 = *(const float4*)&cw[(i+2)*4];
  float4 cw3 = *(const float4*)&cw[(i+3)*4];
  float4 sc;
  sc.x = cw0.x*xk0.x + cw0.y*xk1.x + cw0.z*xk2.x + cw0.w*xk3.x;
  sc.y = cw1.x*xk0.y + cw1.y*xk1.y + cw1.z*xk2.y + cw1.w*xk3.y;
  sc.z = cw2.x*xk0.z + cw2.y*xk1.z + cw2.z*xk2.z + cw2.w*xk3.z;
  sc.w = cw3.x*xk0.w + cw3.y*xk1.w + cw3.z*xk2.w + cw3.w*xk3.w;
  float4 o;
  o.x = sc.x + 0.01f*(l4.x - sc.x);
  o.y = sc.y + 0.01f*(l4.y - sc.y);
  o.z = sc.z + 0.01f*(l4.z - sc.z);
  o.w = sc.w + 0.01f*(l4.w - sc.w);
  *(float4*)&out[gi] = o;
}

extern "C" void kernel_launch(void* const* d_in, const int* in_sizes, int n_in,
                              void* d_out, int out_size, void* d_ws, size_t ws_size,
                              hipStream_t stream) {
  const float* X     = (const float*)d_in[0];
  const float* convw = (const float*)d_in[1];
  const float* Wrec  = (const float*)d_in[2];
  const float* tw1   = (const float*)d_in[3];
  const float* tb1   = (const float*)d_in[4];
  const float* tw2   = (const float*)d_in[5];
  const float* tb2   = (const float*)d_in[6];
  const float* lng   = (const float*)d_in[7];
  const float* lnb   = (const float*)d_in[8];
  float* out = (float*)d_out;
  float* wsf = (float*)d_ws;

  unsigned* cnt = (unsigned*)d_ws;      // 16 counters @ 64B spacing = 256 dwords
  float* fbuf = wsf + 256;              // 2 x 4 x 1024 f values
  float* taup = wsf + 8448;             // 2 x 4 x 256 tau partials
  float* w1hT = wsf + 10496;            // 512 x 1024
  float* xtau = w1hT + 512*1024;        // 8192 x 512

  hipMemsetAsync(d_ws, 0, 1024, stream);   // arrive counters only
  transpose_w1h<<<dim3(32,16), dim3(256), 0, stream>>>(tw1, w1hT);
  gemm_xtau   <<<dim3(8,128),  dim3(256), 0, stream>>>(X, tw1, tb1, xtau);
  liquid_kernel<<<dim3(NWG),   dim3(NTH), 0, stream>>>(X, Wrec, w1hT, tw2, tb2,
                                                       lng, lnb, xtau, cnt, fbuf,
                                                       taup, out);
  finalize_kernel<<<dim3(8192), dim3(256), 0, stream>>>(X, convw, out);
}